// Round 17
// baseline (401.305 us; speedup 1.0000x reference)
//
#include <hip/hip_runtime.h>
#include <math.h>

#define NS   64
#define NOBS 10000
#define NB   256
#define TMAX 2048

// workspace layout (floats)
#define PIP_OFF 0
#define ASW_OFF 64                    // swizzled A_prob, 4096 floats
#define LSE_OFF (64 + 4096)
#define ET_OFF  (64 + 4096 + 64)

__device__ __forceinline__ float wsum64(float v) {
  v += __shfl_xor(v, 1);
  v += __shfl_xor(v, 2);
  v += __shfl_xor(v, 4);
  v += __shfl_xor(v, 8);
  v += __shfl_xor(v, 16);
  v += __shfl_xor(v, 32);
  return v;
}

// DPP row_ror:N within 16-lane rows. Direction probed at prep time.
#define DPPROR(S, N)                                                           \
  __int_as_float(__builtin_amdgcn_update_dpp(                                  \
      0, __float_as_int(S), 0x120 + (N), 0xF, 0xF, true))

// ---------------- precompute: softmax(pi), column-softmax(A), swizzle ------
__global__ __launch_bounds__(64) void prep_small(const float* __restrict__ pi,
                                                 const float* __restrict__ A,
                                                 float* __restrict__ ws) {
  const int l = threadIdx.x;  // 0..63
  const int r = l & 15, c = l >> 4;
  float p = pi[l];
  float m = p;
  m = fmaxf(m, __shfl_xor(m, 1));
  m = fmaxf(m, __shfl_xor(m, 2));
  m = fmaxf(m, __shfl_xor(m, 4));
  m = fmaxf(m, __shfl_xor(m, 8));
  m = fmaxf(m, __shfl_xor(m, 16));
  m = fmaxf(m, __shfl_xor(m, 32));
  float ex = expf(p - m);
  float s = wsum64(ex);
  ws[PIP_OFF + l] = ex / s;

  __shared__ float Ap[NS * NS];
  float cm = -3.0e38f;
  for (int i = 0; i < NS; ++i) cm = fmaxf(cm, A[i * NS + l]);
  float cs = 0.f;
  for (int i = 0; i < NS; ++i) cs += expf(A[i * NS + l] - cm);
  float inv = 1.0f / cs;
  for (int i = 0; i < NS; ++i) Ap[i * NS + l] = expf(A[i * NS + l] - cm) * inv;
  __syncthreads();

  // probe the hardware's row_ror direction: does lane l receive (l-1)&15 ?
  const int probe = __builtin_amdgcn_update_dpp(0, l, 0x121, 0xF, 0xF, true);
  const int dir = ((probe & 15) == ((r - 1) & 15)) ? 1 : -1;  // uniform

  // systolic swizzle matched to measured direction (R14 layout, proven):
  // lane l=(r,c): aw[g][j] = Ap[r+16g][16c + ((r - dir*j)&15)]
  for (int g = 0; g < 4; ++g)
    for (int j = 0; j < 16; ++j)
      ws[ASW_OFF + l * 64 + g * 16 + j] =
          Ap[(r + 16 * g) * NS + (16 * c + ((r - dir * j) & 15))];
}

// ---------------- precompute: per-state emission logsumexp ----------------
__global__ __launch_bounds__(256) void emis_lse(const float* __restrict__ E,
                                                float* __restrict__ ws) {
  const int s = blockIdx.x;  // state
  const float* row = E + (size_t)s * NOBS;
  __shared__ float red[4];
  float m = -3.0e38f;
  for (int o = threadIdx.x; o < NOBS; o += 256) m = fmaxf(m, row[o]);
  m = fmaxf(m, __shfl_xor(m, 1));
  m = fmaxf(m, __shfl_xor(m, 2));
  m = fmaxf(m, __shfl_xor(m, 4));
  m = fmaxf(m, __shfl_xor(m, 8));
  m = fmaxf(m, __shfl_xor(m, 16));
  m = fmaxf(m, __shfl_xor(m, 32));
  const int wid = threadIdx.x >> 6;
  if ((threadIdx.x & 63) == 0) red[wid] = m;
  __syncthreads();
  m = fmaxf(fmaxf(red[0], red[1]), fmaxf(red[2], red[3]));
  __syncthreads();
  float sum = 0.f;
  for (int o = threadIdx.x; o < NOBS; o += 256) sum += expf(row[o] - m);
  sum = wsum64(sum);
  if ((threadIdx.x & 63) == 0) red[wid] = sum;
  __syncthreads();
  if (threadIdx.x == 0)
    ws[LSE_OFF + s] = m + logf(red[0] + red[1] + red[2] + red[3]);
}

// ---------------- precompute: EprobT[obs*64 + s] = exp(E[s,obs] - lse[s]) ----
__global__ __launch_bounds__(256) void emis_fill(const float* __restrict__ E,
                                                 float* __restrict__ ws) {
  const int idx = blockIdx.x * 256 + threadIdx.x;  // = obs*64 + s
  if (idx >= NS * NOBS) return;
  const int s = idx & 63;
  const int obs = idx >> 6;
  ws[ET_OFF + idx] = expf(E[(size_t)s * NOBS + obs] - ws[LSE_OFF + s]);
}

// ---------------- forward recursion: 1 batch = 1 block = 1 wave ----------------
// EXACT R14 structure (proven absmax 0.0, 360us) + ONE change: mul-first
// chain init (q = aw*rot then 7 fmas, replacing zero-init + 8 fmas;
// fmaf(a,b,0) == a*b bitwise for our non-negative operands). Single-variable
// bisection of the R15/R16 absmax-128 defect: if this round is clean, the
// peel machinery was the bug; if 128, mul-first is.

#define PIN8(i)                                                                \
  asm volatile("" : "+v"(aw[(i)]), "+v"(aw[(i) + 1]), "+v"(aw[(i) + 2]),       \
                    "+v"(aw[(i) + 3]), "+v"(aw[(i) + 4]), "+v"(aw[(i) + 5]),   \
                    "+v"(aw[(i) + 6]), "+v"(aw[(i) + 7]))
#define PIN_AW() do { PIN8(0); PIN8(8); PIN8(16); PIN8(24);                    \
                      PIN8(32); PIN8(40); PIN8(48); PIN8(56); } while (0)

// stage 64 emission rows of a chunk (x values in XS) into half HALF of ebuf
#define STAGE_CHUNK(XS, HALF) do {                                             \
    _Pragma("unroll")                                                          \
    for (int k_ = 0; k_ < 64; ++k_) {                                          \
      const int xt_ = __builtin_amdgcn_readlane((XS), k_);                     \
      const float* gp_ = ET + ((size_t)(unsigned)xt_ << 6) + lane;             \
      __builtin_amdgcn_global_load_lds(gp_, &ebuf[(((HALF) << 6) + k_) << 6],  \
                                       4, 0, 0);                               \
    } } while (0)

#define EREAD(DST, ADDR, IMM)                                                  \
  asm volatile("ds_read_b32 %0, %1 offset:" #IMM : "=v"(DST) : "v"(ADDR))

#define STEP(u, EC) do {                                                       \
    const int t_ = t0 + (u);                                                   \
    const float e_ = EC[(u)];                                                  \
    float es_;                                                                 \
    if (((u) & 1) != 0) { /* exact pow-2 rescale every 2 steps */              \
      const unsigned srf_ = __builtin_amdgcn_readfirstlane(__float_as_uint(s));\
      const int se_ = (int)((srf_ >> 23) & 0xFFu) - 127;                       \
      es_ = e_ * __uint_as_float((unsigned)(127 - se_) << 23);                 \
      E2 += se_;                                                               \
    } else { es_ = e_; }                                                       \
    float rot[16];                                                             \
    rot[0] = s;                                                                \
    rot[1] = DPPROR(s, 1);   rot[2] = DPPROR(s, 2);   rot[3] = DPPROR(s, 3);   \
    rot[4] = DPPROR(s, 4);   rot[5] = DPPROR(s, 5);   rot[6] = DPPROR(s, 6);   \
    rot[7] = DPPROR(s, 7);   rot[8] = DPPROR(s, 8);   rot[9] = DPPROR(s, 9);   \
    rot[10] = DPPROR(s, 10); rot[11] = DPPROR(s, 11); rot[12] = DPPROR(s, 12); \
    rot[13] = DPPROR(s, 13); rot[14] = DPPROR(s, 14); rot[15] = DPPROR(s, 15); \
    float q0a_ = aw[0]  * rot[0];                                              \
    float q1a_ = aw[16] * rot[0];                                              \
    float q2a_ = aw[32] * rot[0];                                              \
    float q3a_ = aw[48] * rot[0];                                              \
    float q0b_ = aw[8]  * rot[8];                                              \
    float q1b_ = aw[24] * rot[8];                                              \
    float q2b_ = aw[40] * rot[8];                                              \
    float q3b_ = aw[56] * rot[8];                                              \
    _Pragma("unroll")                                                          \
    for (int j_ = 1; j_ < 8; ++j_) {                                           \
      q0a_ = fmaf(aw[j_],      rot[j_], q0a_);                                 \
      q1a_ = fmaf(aw[16 + j_], rot[j_], q1a_);                                 \
      q2a_ = fmaf(aw[32 + j_], rot[j_], q2a_);                                 \
      q3a_ = fmaf(aw[48 + j_], rot[j_], q3a_);                                 \
      q0b_ = fmaf(aw[8 + j_],  rot[8 + j_], q0b_);                             \
      q1b_ = fmaf(aw[24 + j_], rot[8 + j_], q1b_);                             \
      q2b_ = fmaf(aw[40 + j_], rot[8 + j_], q2b_);                             \
      q3b_ = fmaf(aw[56 + j_], rot[8 + j_], q3b_);                             \
    }                                                                          \
    const float q0_ = q0a_ + q0b_;                                             \
    const float q1_ = q1a_ + q1b_;                                             \
    const float q2_ = q2a_ + q2b_;                                             \
    const float q3_ = q3a_ + q3b_;                                             \
    /* stage1 (xor32) reduce-scatter: give partner's group-pair, keep ours */  \
    float em_ = c1m ? q0_ : q2_;           /* give A */                        \
    float en_ = c1m ? q1_ : q3_;           /* give B */                        \
    float emc_, enc_;                                                          \
    asm("v_mov_b32 %0, %1" : "=v"(emc_) : "v"(em_));                           \
    asm("v_mov_b32 %0, %1" : "=v"(enc_) : "v"(en_));                           \
    asm("v_permlane32_swap_b32 %0, %1" : "+v"(em_), "+v"(emc_));               \
    asm("v_permlane32_swap_b32 %0, %1" : "+v"(en_), "+v"(enc_));               \
    const float pm_ = inA32 ? em_ : emc_;  /* partner's give A (probed) */     \
    const float pn_ = inA32 ? en_ : enc_;  /* partner's give B (probed) */     \
    const float ka_ = c1m ? q2_ : q0_;     /* keep A = q[2c1]   */             \
    const float kb_ = c1m ? q3_ : q1_;     /* keep B = q[2c1+1] */             \
    const float ua_ = ka_ + pm_;                                               \
    const float ub_ = kb_ + pn_;                                               \
    /* stage2 (xor16): give partner's member, keep ours */                     \
    float gv_ = c0m ? ua_ : ub_;                                               \
    float gvc_;                                                                \
    asm("v_mov_b32 %0, %1" : "=v"(gvc_) : "v"(gv_));                           \
    asm("v_permlane16_swap_b32 %0, %1" : "+v"(gv_), "+v"(gvc_));               \
    const float pg_ = inA16 ? gv_ : gvc_;  /* partner's give (probed) */       \
    const float kp_ = c0m ? ub_ : ua_;                                         \
    const float fin_ = kp_ + pg_;                                              \
    const float w_ = es_ * ((t_ == 0) ? pip : fin_);                           \
    if (t_ == Tn - 1) { vs = w_; e2s = E2; }                                   \
    s = w_;                                                                    \
  } while (0)

// one 4-step group: issue next group's 4 e-reads, exact-wait current's, run 4
#define GROUP(T0, ECUR, ENXT) do {                                             \
    const int t0 = (T0);                                                       \
    { const unsigned ea_ =                                                     \
          ebase + ((unsigned)(((t0 + 4) & 127)) << 8) + ((unsigned)lane << 2); \
      EREAD(ENXT[0], ea_, 0);   EREAD(ENXT[1], ea_, 256);                      \
      EREAD(ENXT[2], ea_, 512); EREAD(ENXT[3], ea_, 768); }                    \
    asm volatile("s_waitcnt lgkmcnt(4)");                                      \
    __builtin_amdgcn_sched_barrier(0);                                         \
    STEP(0, ECUR); STEP(1, ECUR); STEP(2, ECUR); STEP(3, ECUR);                \
  } while (0)

__global__ void __attribute__((amdgpu_flat_work_group_size(64, 64)))
__attribute__((amdgpu_waves_per_eu(1, 1)))
hmm_fwd(const int* __restrict__ x, const int* __restrict__ T,
        const float* __restrict__ ws, float* __restrict__ out) {
  const int lane = threadIdx.x;
  const int b = blockIdx.x;
  const int cgrp = lane >> 4;
  const bool c0m = (cgrp & 1) != 0;
  const bool c1m = (cgrp & 2) != 0;
  const float* __restrict__ ET = ws + ET_OFF;
  const int* __restrict__ xb = x + (size_t)b * TMAX;
  const int Tn = T[b];

  __shared__ __align__(16) float ebuf[128 * 64];  // 32 KB, 2 chunk halves
  const unsigned ebase = (unsigned)(size_t)ebuf;  // flat->LDS trunc

  // probe swap routing (R11 lesson: never assume direction semantics)
  bool inA32, inA16;
  {
    float qa = __int_as_float(lane), qb;
    asm("v_mov_b32 %0, %1" : "=v"(qb) : "v"(qa));
    asm("v_permlane32_swap_b32 %0, %1" : "+v"(qa), "+v"(qb));
    inA32 = (__float_as_int(qa) == (lane ^ 32));
    float pa = __int_as_float(lane), pb;
    asm("v_mov_b32 %0, %1" : "=v"(pb) : "v"(pa));
    asm("v_permlane16_swap_b32 %0, %1" : "+v"(pa), "+v"(pb));
    inA16 = (__float_as_int(pa) == (lane ^ 16));
  }

  // swizzled A tile for this lane: aw[g*16+j], pinned resident in VGPRs
  float aw[NS];
  {
    const float4* ar = (const float4*)(ws + ASW_OFF + lane * NS);
#pragma unroll
    for (int q = 0; q < 16; ++q) {
      float4 f = ar[q];
      aw[4 * q + 0] = f.x; aw[4 * q + 1] = f.y;
      aw[4 * q + 2] = f.z; aw[4 * q + 3] = f.w;
    }
  }
  PIN_AW();

  const float pip = ws[PIP_OFF + lane];

  // stage chunk 0, drain, prime group-0 e-reads
  int xcur = xb[lane];
  STAGE_CHUNK(xcur, 0);
  int xnext = xb[64 + lane];
  asm volatile("s_waitcnt vmcnt(0)" ::: "memory");

  float eA[4], eB[4];
  {
    const unsigned ea_ = ebase + ((unsigned)lane << 2);
    EREAD(eA[0], ea_, 0);   EREAD(eA[1], ea_, 256);
    EREAD(eA[2], ea_, 512); EREAD(eA[3], ea_, 768);
  }

  float s = 1.0f;   // exponent 0 -> se=0 at t=0
  float vs = 0.f;
  int E2 = 0, e2s = 0;

  const int nch = (Tn + 63) >> 6;
  for (int c = 0; c < nch; ++c) {
    const int tb = c << 6;
    if (c + 1 < TMAX / 64) STAGE_CHUNK(xnext, (c + 1) & 1);
    xnext = ((c + 2) < TMAX / 64) ? xb[((c + 2) << 6) + lane] : 0;
#pragma unroll 1
    for (int gp = 0; gp < 7; ++gp) {    // groups 0..13
      GROUP(tb + (gp << 3), eA, eB);
      GROUP(tb + (gp << 3) + 4, eB, eA);
    }
    GROUP(tb + 56, eA, eB);             // group 14
    // drain staging of chunk c+1 before group 15 issues next-chunk reads
    asm volatile("s_waitcnt vmcnt(0)" ::: "memory");
    GROUP(tb + 60, eB, eA);             // group 15 (loads eA for next chunk)
  }

  const float sf = wsum64(vs);
  if (lane == 0) {
    const double lp = (double)logf(sf) + (double)e2s * 0.6931471805599453;
    out[b] = (float)lp;
  }
}

extern "C" void kernel_launch(void* const* d_in, const int* in_sizes, int n_in,
                              void* d_out, int out_size, void* d_ws, size_t ws_size,
                              hipStream_t stream) {
  const int*   x  = (const int*)d_in[0];
  const int*   T  = (const int*)d_in[1];
  const float* pi = (const float*)d_in[2];
  const float* A  = (const float*)d_in[3];
  const float* E  = (const float*)d_in[4];
  float* out = (float*)d_out;
  float* ws  = (float*)d_ws;

  prep_small<<<1, 64, 0, stream>>>(pi, A, ws);
  emis_lse<<<NS, 256, 0, stream>>>(E, ws);
  emis_fill<<<(NS * NOBS + 255) / 256, 256, 0, stream>>>(E, ws);
  hmm_fwd<<<NB, 64, 0, stream>>>(x, T, ws, out);
}

// Round 18
// 397.642 us; speedup vs baseline: 1.0092x; 1.0092x over previous
//
#include <hip/hip_runtime.h>
#include <math.h>

#define NS   64
#define NOBS 10000
#define NB   256
#define TMAX 2048
#define REP  4     // redundant replication: 4 blocks/CU raise utilization (DVFS probe)

// workspace layout (floats)
#define PIP_OFF 0
#define ASW_OFF 64                    // swizzled A_prob, 4096 floats
#define LSE_OFF (64 + 4096)
#define ET_OFF  (64 + 4096 + 64)

__device__ __forceinline__ float wsum64(float v) {
  v += __shfl_xor(v, 1);
  v += __shfl_xor(v, 2);
  v += __shfl_xor(v, 4);
  v += __shfl_xor(v, 8);
  v += __shfl_xor(v, 16);
  v += __shfl_xor(v, 32);
  return v;
}

// DPP row_ror:N within 16-lane rows. Direction probed at prep time.
#define DPPROR(S, N)                                                           \
  __int_as_float(__builtin_amdgcn_update_dpp(                                  \
      0, __float_as_int(S), 0x120 + (N), 0xF, 0xF, true))

// ---------------- precompute: softmax(pi), column-softmax(A), swizzle ------
__global__ __launch_bounds__(64) void prep_small(const float* __restrict__ pi,
                                                 const float* __restrict__ A,
                                                 float* __restrict__ ws) {
  const int l = threadIdx.x;  // 0..63
  const int r = l & 15, c = l >> 4;
  float p = pi[l];
  float m = p;
  m = fmaxf(m, __shfl_xor(m, 1));
  m = fmaxf(m, __shfl_xor(m, 2));
  m = fmaxf(m, __shfl_xor(m, 4));
  m = fmaxf(m, __shfl_xor(m, 8));
  m = fmaxf(m, __shfl_xor(m, 16));
  m = fmaxf(m, __shfl_xor(m, 32));
  float ex = expf(p - m);
  float s = wsum64(ex);
  ws[PIP_OFF + l] = ex / s;

  __shared__ float Ap[NS * NS];
  float cm = -3.0e38f;
  for (int i = 0; i < NS; ++i) cm = fmaxf(cm, A[i * NS + l]);
  float cs = 0.f;
  for (int i = 0; i < NS; ++i) cs += expf(A[i * NS + l] - cm);
  float inv = 1.0f / cs;
  for (int i = 0; i < NS; ++i) Ap[i * NS + l] = expf(A[i * NS + l] - cm) * inv;
  __syncthreads();

  // probe the hardware's row_ror direction: does lane l receive (l-1)&15 ?
  const int probe = __builtin_amdgcn_update_dpp(0, l, 0x121, 0xF, 0xF, true);
  const int dir = ((probe & 15) == ((r - 1) & 15)) ? 1 : -1;  // uniform

  // systolic swizzle matched to measured direction (R14 layout, proven):
  // lane l=(r,c): aw[g][j] = Ap[r+16g][16c + ((r - dir*j)&15)]
  for (int g = 0; g < 4; ++g)
    for (int j = 0; j < 16; ++j)
      ws[ASW_OFF + l * 64 + g * 16 + j] =
          Ap[(r + 16 * g) * NS + (16 * c + ((r - dir * j) & 15))];
}

// ---------------- precompute: per-state emission logsumexp ----------------
__global__ __launch_bounds__(256) void emis_lse(const float* __restrict__ E,
                                                float* __restrict__ ws) {
  const int s = blockIdx.x;  // state
  const float* row = E + (size_t)s * NOBS;
  __shared__ float red[4];
  float m = -3.0e38f;
  for (int o = threadIdx.x; o < NOBS; o += 256) m = fmaxf(m, row[o]);
  m = fmaxf(m, __shfl_xor(m, 1));
  m = fmaxf(m, __shfl_xor(m, 2));
  m = fmaxf(m, __shfl_xor(m, 4));
  m = fmaxf(m, __shfl_xor(m, 8));
  m = fmaxf(m, __shfl_xor(m, 16));
  m = fmaxf(m, __shfl_xor(m, 32));
  const int wid = threadIdx.x >> 6;
  if ((threadIdx.x & 63) == 0) red[wid] = m;
  __syncthreads();
  m = fmaxf(fmaxf(red[0], red[1]), fmaxf(red[2], red[3]));
  __syncthreads();
  float sum = 0.f;
  for (int o = threadIdx.x; o < NOBS; o += 256) sum += expf(row[o] - m);
  sum = wsum64(sum);
  if ((threadIdx.x & 63) == 0) red[wid] = sum;
  __syncthreads();
  if (threadIdx.x == 0)
    ws[LSE_OFF + s] = m + logf(red[0] + red[1] + red[2] + red[3]);
}

// ---------------- precompute: EprobT[obs*64 + s] = exp(E[s,obs] - lse[s]) ----
__global__ __launch_bounds__(256) void emis_fill(const float* __restrict__ E,
                                                 float* __restrict__ ws) {
  const int idx = blockIdx.x * 256 + threadIdx.x;  // = obs*64 + s
  if (idx >= NS * NOBS) return;
  const int s = idx & 63;
  const int obs = idx >> 6;
  ws[ET_OFF + idx] = expf(E[(size_t)s * NOBS + obs] - ws[LSE_OFF + s]);
}

// ---------------- forward recursion: 1 batch = 1 wave; 4 replica blocks ----
// EXACT R17 kernel body (proven absmax 0.0, 360us). ONE change: grid = NB*REP
// with b = blockIdx.x & (NB-1) -- each batch computed identically by REP
// blocks (bitwise-identical writes, benign). Purpose: raise chip utilization
// 4x (4 blocks/CU, 1 wave/SIMD) to test whether the unexplained 2x gap
// between the ~200cy/step chain+issue model and the measured 422cy/step
// (@nominal clock) is DVFS downclocking at 9% utilization.

#define PIN8(i)                                                                \
  asm volatile("" : "+v"(aw[(i)]), "+v"(aw[(i) + 1]), "+v"(aw[(i) + 2]),       \
                    "+v"(aw[(i) + 3]), "+v"(aw[(i) + 4]), "+v"(aw[(i) + 5]),   \
                    "+v"(aw[(i) + 6]), "+v"(aw[(i) + 7]))
#define PIN_AW() do { PIN8(0); PIN8(8); PIN8(16); PIN8(24);                    \
                      PIN8(32); PIN8(40); PIN8(48); PIN8(56); } while (0)

// stage 64 emission rows of a chunk (x values in XS) into half HALF of ebuf
#define STAGE_CHUNK(XS, HALF) do {                                             \
    _Pragma("unroll")                                                          \
    for (int k_ = 0; k_ < 64; ++k_) {                                          \
      const int xt_ = __builtin_amdgcn_readlane((XS), k_);                     \
      const float* gp_ = ET + ((size_t)(unsigned)xt_ << 6) + lane;             \
      __builtin_amdgcn_global_load_lds(gp_, &ebuf[(((HALF) << 6) + k_) << 6],  \
                                       4, 0, 0);                               \
    } } while (0)

#define EREAD(DST, ADDR, IMM)                                                  \
  asm volatile("ds_read_b32 %0, %1 offset:" #IMM : "=v"(DST) : "v"(ADDR))

#define STEP(u, EC) do {                                                       \
    const int t_ = t0 + (u);                                                   \
    const float e_ = EC[(u)];                                                  \
    float es_;                                                                 \
    if (((u) & 1) != 0) { /* exact pow-2 rescale every 2 steps */              \
      const unsigned srf_ = __builtin_amdgcn_readfirstlane(__float_as_uint(s));\
      const int se_ = (int)((srf_ >> 23) & 0xFFu) - 127;                       \
      es_ = e_ * __uint_as_float((unsigned)(127 - se_) << 23);                 \
      E2 += se_;                                                               \
    } else { es_ = e_; }                                                       \
    float rot[16];                                                             \
    rot[0] = s;                                                                \
    rot[1] = DPPROR(s, 1);   rot[2] = DPPROR(s, 2);   rot[3] = DPPROR(s, 3);   \
    rot[4] = DPPROR(s, 4);   rot[5] = DPPROR(s, 5);   rot[6] = DPPROR(s, 6);   \
    rot[7] = DPPROR(s, 7);   rot[8] = DPPROR(s, 8);   rot[9] = DPPROR(s, 9);   \
    rot[10] = DPPROR(s, 10); rot[11] = DPPROR(s, 11); rot[12] = DPPROR(s, 12); \
    rot[13] = DPPROR(s, 13); rot[14] = DPPROR(s, 14); rot[15] = DPPROR(s, 15); \
    float q0a_ = aw[0]  * rot[0];                                              \
    float q1a_ = aw[16] * rot[0];                                              \
    float q2a_ = aw[32] * rot[0];                                              \
    float q3a_ = aw[48] * rot[0];                                              \
    float q0b_ = aw[8]  * rot[8];                                              \
    float q1b_ = aw[24] * rot[8];                                              \
    float q2b_ = aw[40] * rot[8];                                              \
    float q3b_ = aw[56] * rot[8];                                              \
    _Pragma("unroll")                                                          \
    for (int j_ = 1; j_ < 8; ++j_) {                                           \
      q0a_ = fmaf(aw[j_],      rot[j_], q0a_);                                 \
      q1a_ = fmaf(aw[16 + j_], rot[j_], q1a_);                                 \
      q2a_ = fmaf(aw[32 + j_], rot[j_], q2a_);                                 \
      q3a_ = fmaf(aw[48 + j_], rot[j_], q3a_);                                 \
      q0b_ = fmaf(aw[8 + j_],  rot[8 + j_], q0b_);                             \
      q1b_ = fmaf(aw[24 + j_], rot[8 + j_], q1b_);                             \
      q2b_ = fmaf(aw[40 + j_], rot[8 + j_], q2b_);                             \
      q3b_ = fmaf(aw[56 + j_], rot[8 + j_], q3b_);                             \
    }                                                                          \
    const float q0_ = q0a_ + q0b_;                                             \
    const float q1_ = q1a_ + q1b_;                                             \
    const float q2_ = q2a_ + q2b_;                                             \
    const float q3_ = q3a_ + q3b_;                                             \
    /* stage1 (xor32) reduce-scatter: give partner's group-pair, keep ours */  \
    float em_ = c1m ? q0_ : q2_;           /* give A */                        \
    float en_ = c1m ? q1_ : q3_;           /* give B */                        \
    float emc_, enc_;                                                          \
    asm("v_mov_b32 %0, %1" : "=v"(emc_) : "v"(em_));                           \
    asm("v_mov_b32 %0, %1" : "=v"(enc_) : "v"(en_));                           \
    asm("v_permlane32_swap_b32 %0, %1" : "+v"(em_), "+v"(emc_));               \
    asm("v_permlane32_swap_b32 %0, %1" : "+v"(en_), "+v"(enc_));               \
    const float pm_ = inA32 ? em_ : emc_;  /* partner's give A (probed) */     \
    const float pn_ = inA32 ? en_ : enc_;  /* partner's give B (probed) */     \
    const float ka_ = c1m ? q2_ : q0_;     /* keep A = q[2c1]   */             \
    const float kb_ = c1m ? q3_ : q1_;     /* keep B = q[2c1+1] */             \
    const float ua_ = ka_ + pm_;                                               \
    const float ub_ = kb_ + pn_;                                               \
    /* stage2 (xor16): give partner's member, keep ours */                     \
    float gv_ = c0m ? ua_ : ub_;                                               \
    float gvc_;                                                                \
    asm("v_mov_b32 %0, %1" : "=v"(gvc_) : "v"(gv_));                           \
    asm("v_permlane16_swap_b32 %0, %1" : "+v"(gv_), "+v"(gvc_));               \
    const float pg_ = inA16 ? gv_ : gvc_;  /* partner's give (probed) */       \
    const float kp_ = c0m ? ub_ : ua_;                                         \
    const float fin_ = kp_ + pg_;                                              \
    const float w_ = es_ * ((t_ == 0) ? pip : fin_);                           \
    if (t_ == Tn - 1) { vs = w_; e2s = E2; }                                   \
    s = w_;                                                                    \
  } while (0)

// one 4-step group: issue next group's 4 e-reads, exact-wait current's, run 4
#define GROUP(T0, ECUR, ENXT) do {                                             \
    const int t0 = (T0);                                                       \
    { const unsigned ea_ =                                                     \
          ebase + ((unsigned)(((t0 + 4) & 127)) << 8) + ((unsigned)lane << 2); \
      EREAD(ENXT[0], ea_, 0);   EREAD(ENXT[1], ea_, 256);                      \
      EREAD(ENXT[2], ea_, 512); EREAD(ENXT[3], ea_, 768); }                    \
    asm volatile("s_waitcnt lgkmcnt(4)");                                      \
    __builtin_amdgcn_sched_barrier(0);                                         \
    STEP(0, ECUR); STEP(1, ECUR); STEP(2, ECUR); STEP(3, ECUR);                \
  } while (0)

__global__ void __attribute__((amdgpu_flat_work_group_size(64, 64)))
__attribute__((amdgpu_waves_per_eu(1, 1)))
hmm_fwd(const int* __restrict__ x, const int* __restrict__ T,
        const float* __restrict__ ws, float* __restrict__ out) {
  const int lane = threadIdx.x;
  const int b = blockIdx.x & (NB - 1);   // REP replicas compute identical bits
  const int cgrp = lane >> 4;
  const bool c0m = (cgrp & 1) != 0;
  const bool c1m = (cgrp & 2) != 0;
  const float* __restrict__ ET = ws + ET_OFF;
  const int* __restrict__ xb = x + (size_t)b * TMAX;
  const int Tn = T[b];

  __shared__ __align__(16) float ebuf[128 * 64];  // 32 KB, 2 chunk halves
  const unsigned ebase = (unsigned)(size_t)ebuf;  // flat->LDS trunc

  // probe swap routing (R11 lesson: never assume direction semantics)
  bool inA32, inA16;
  {
    float qa = __int_as_float(lane), qb;
    asm("v_mov_b32 %0, %1" : "=v"(qb) : "v"(qa));
    asm("v_permlane32_swap_b32 %0, %1" : "+v"(qa), "+v"(qb));
    inA32 = (__float_as_int(qa) == (lane ^ 32));
    float pa = __int_as_float(lane), pb;
    asm("v_mov_b32 %0, %1" : "=v"(pb) : "v"(pa));
    asm("v_permlane16_swap_b32 %0, %1" : "+v"(pa), "+v"(pb));
    inA16 = (__float_as_int(pa) == (lane ^ 16));
  }

  // swizzled A tile for this lane: aw[g*16+j], pinned resident in VGPRs
  float aw[NS];
  {
    const float4* ar = (const float4*)(ws + ASW_OFF + lane * NS);
#pragma unroll
    for (int q = 0; q < 16; ++q) {
      float4 f = ar[q];
      aw[4 * q + 0] = f.x; aw[4 * q + 1] = f.y;
      aw[4 * q + 2] = f.z; aw[4 * q + 3] = f.w;
    }
  }
  PIN_AW();

  const float pip = ws[PIP_OFF + lane];

  // stage chunk 0, drain, prime group-0 e-reads
  int xcur = xb[lane];
  STAGE_CHUNK(xcur, 0);
  int xnext = xb[64 + lane];
  asm volatile("s_waitcnt vmcnt(0)" ::: "memory");

  float eA[4], eB[4];
  {
    const unsigned ea_ = ebase + ((unsigned)lane << 2);
    EREAD(eA[0], ea_, 0);   EREAD(eA[1], ea_, 256);
    EREAD(eA[2], ea_, 512); EREAD(eA[3], ea_, 768);
  }

  float s = 1.0f;   // exponent 0 -> se=0 at t=0
  float vs = 0.f;
  int E2 = 0, e2s = 0;

  const int nch = (Tn + 63) >> 6;
  for (int c = 0; c < nch; ++c) {
    const int tb = c << 6;
    if (c + 1 < TMAX / 64) STAGE_CHUNK(xnext, (c + 1) & 1);
    xnext = ((c + 2) < TMAX / 64) ? xb[((c + 2) << 6) + lane] : 0;
#pragma unroll 1
    for (int gp = 0; gp < 7; ++gp) {    // groups 0..13
      GROUP(tb + (gp << 3), eA, eB);
      GROUP(tb + (gp << 3) + 4, eB, eA);
    }
    GROUP(tb + 56, eA, eB);             // group 14
    // drain staging of chunk c+1 before group 15 issues next-chunk reads
    asm volatile("s_waitcnt vmcnt(0)" ::: "memory");
    GROUP(tb + 60, eB, eA);             // group 15 (loads eA for next chunk)
  }

  const float sf = wsum64(vs);
  if (lane == 0) {
    const double lp = (double)logf(sf) + (double)e2s * 0.6931471805599453;
    out[b] = (float)lp;
  }
}

extern "C" void kernel_launch(void* const* d_in, const int* in_sizes, int n_in,
                              void* d_out, int out_size, void* d_ws, size_t ws_size,
                              hipStream_t stream) {
  const int*   x  = (const int*)d_in[0];
  const int*   T  = (const int*)d_in[1];
  const float* pi = (const float*)d_in[2];
  const float* A  = (const float*)d_in[3];
  const float* E  = (const float*)d_in[4];
  float* out = (float*)d_out;
  float* ws  = (float*)d_ws;

  prep_small<<<1, 64, 0, stream>>>(pi, A, ws);
  emis_lse<<<NS, 256, 0, stream>>>(E, ws);
  emis_fill<<<(NS * NOBS + 255) / 256, 256, 0, stream>>>(E, ws);
  hmm_fwd<<<NB * REP, 64, 0, stream>>>(x, T, ws, out);
}

// Round 19
// 381.221 us; speedup vs baseline: 1.0527x; 1.0431x over previous
//
#include <hip/hip_runtime.h>
#include <math.h>

#define NS   64
#define NOBS 10000
#define NB   256
#define TMAX 2048

// workspace layout (floats)
#define PIP_OFF 0
#define ASW_OFF 64                    // group-permuted swizzled A_prob
#define LSE_OFF (64 + 4096)
#define ET_OFF  (64 + 4096 + 64)

__device__ __forceinline__ float wsum64(float v) {
  v += __shfl_xor(v, 1);
  v += __shfl_xor(v, 2);
  v += __shfl_xor(v, 4);
  v += __shfl_xor(v, 8);
  v += __shfl_xor(v, 16);
  v += __shfl_xor(v, 32);
  return v;
}

// DPP row_ror:N within 16-lane rows. Direction probed at prep time.
#define DPPROR(S, N)                                                           \
  __int_as_float(__builtin_amdgcn_update_dpp(                                  \
      0, __float_as_int(S), 0x120 + (N), 0xF, 0xF, true))

// ---------------- precompute: softmax(pi), column-softmax(A), swizzle ------
__global__ __launch_bounds__(64) void prep_small(const float* __restrict__ pi,
                                                 const float* __restrict__ A,
                                                 float* __restrict__ ws) {
  const int l = threadIdx.x;  // 0..63
  const int r = l & 15, c = l >> 4;
  float p = pi[l];
  float m = p;
  m = fmaxf(m, __shfl_xor(m, 1));
  m = fmaxf(m, __shfl_xor(m, 2));
  m = fmaxf(m, __shfl_xor(m, 4));
  m = fmaxf(m, __shfl_xor(m, 8));
  m = fmaxf(m, __shfl_xor(m, 16));
  m = fmaxf(m, __shfl_xor(m, 32));
  float ex = expf(p - m);
  float s = wsum64(ex);
  ws[PIP_OFF + l] = ex / s;

  __shared__ float Ap[NS * NS];
  float cm = -3.0e38f;
  for (int i = 0; i < NS; ++i) cm = fmaxf(cm, A[i * NS + l]);
  float cs = 0.f;
  for (int i = 0; i < NS; ++i) cs += expf(A[i * NS + l] - cm);
  float inv = 1.0f / cs;
  for (int i = 0; i < NS; ++i) Ap[i * NS + l] = expf(A[i * NS + l] - cm) * inv;
  __syncthreads();

  // probe the hardware's row_ror direction: does lane l receive (l-1)&15 ?
  const int probe = __builtin_amdgcn_update_dpp(0, l, 0x121, 0xF, 0xF, true);
  const int dir = ((probe & 15) == ((r - 1) & 15)) ? 1 : -1;  // uniform

  // systolic swizzle + GROUP-PERMUTED accumulator order: slot m holds row-
  // group (c ^ m), so q0/q1 are always the KEEP pair (own group / xor16-buddy)
  // and q2/q3 always the GIVE pair -- butterfly needs zero give/keep selects.
  // Verified: lane l ends with state r+16c = l (canonical), same chunk-sum
  // association as R17 -> bitwise identical.
  for (int m2 = 0; m2 < 4; ++m2)
    for (int j = 0; j < 16; ++j)
      ws[ASW_OFF + l * 64 + m2 * 16 + j] =
          Ap[(r + 16 * (c ^ m2)) * NS + (16 * c + ((r - dir * j) & 15))];
}

// ---------------- precompute: per-state emission logsumexp ----------------
__global__ __launch_bounds__(256) void emis_lse(const float* __restrict__ E,
                                                float* __restrict__ ws) {
  const int s = blockIdx.x;  // state
  const float* row = E + (size_t)s * NOBS;
  __shared__ float red[4];
  float m = -3.0e38f;
  for (int o = threadIdx.x; o < NOBS; o += 256) m = fmaxf(m, row[o]);
  m = fmaxf(m, __shfl_xor(m, 1));
  m = fmaxf(m, __shfl_xor(m, 2));
  m = fmaxf(m, __shfl_xor(m, 4));
  m = fmaxf(m, __shfl_xor(m, 8));
  m = fmaxf(m, __shfl_xor(m, 16));
  m = fmaxf(m, __shfl_xor(m, 32));
  const int wid = threadIdx.x >> 6;
  if ((threadIdx.x & 63) == 0) red[wid] = m;
  __syncthreads();
  m = fmaxf(fmaxf(red[0], red[1]), fmaxf(red[2], red[3]));
  __syncthreads();
  float sum = 0.f;
  for (int o = threadIdx.x; o < NOBS; o += 256) sum += expf(row[o] - m);
  sum = wsum64(sum);
  if ((threadIdx.x & 63) == 0) red[wid] = sum;
  __syncthreads();
  if (threadIdx.x == 0)
    ws[LSE_OFF + s] = m + logf(red[0] + red[1] + red[2] + red[3]);
}

// ---------------- precompute: EprobT[obs*64 + s] = exp(E[s,obs] - lse[s]) ----
__global__ __launch_bounds__(256) void emis_fill(const float* __restrict__ E,
                                                 float* __restrict__ ws) {
  const int idx = blockIdx.x * 256 + threadIdx.x;  // = obs*64 + s
  if (idx >= NS * NOBS) return;
  const int s = idx & 63;
  const int obs = idx >> 6;
  ws[ET_OFF + idx] = expf(E[(size_t)s * NOBS + obs] - ws[LSE_OFF + s]);
}

// ---------------- forward recursion: 1 batch = 1 block = 1 wave ----------------
// R17 (proven absmax 0.0, 360us) + ONE change: group-permuted swizzle baking
// give/keep order into aw -> butterfly drops all 6 give/keep cndmasks.
// stage1: give q2,q3 (partner's q2 = my group over its chunk); stage2: give
// ub. Probed routing (inA32/inA16) retained. No peel (proven buggy), chains/
// rescale/staging byte-identical to R17.

#define PIN8(i)                                                                \
  asm volatile("" : "+v"(aw[(i)]), "+v"(aw[(i) + 1]), "+v"(aw[(i) + 2]),       \
                    "+v"(aw[(i) + 3]), "+v"(aw[(i) + 4]), "+v"(aw[(i) + 5]),   \
                    "+v"(aw[(i) + 6]), "+v"(aw[(i) + 7]))
#define PIN_AW() do { PIN8(0); PIN8(8); PIN8(16); PIN8(24);                    \
                      PIN8(32); PIN8(40); PIN8(48); PIN8(56); } while (0)

// stage 64 emission rows of a chunk (x values in XS) into half HALF of ebuf
#define STAGE_CHUNK(XS, HALF) do {                                             \
    _Pragma("unroll")                                                          \
    for (int k_ = 0; k_ < 64; ++k_) {                                          \
      const int xt_ = __builtin_amdgcn_readlane((XS), k_);                     \
      const float* gp_ = ET + ((size_t)(unsigned)xt_ << 6) + lane;             \
      __builtin_amdgcn_global_load_lds(gp_, &ebuf[(((HALF) << 6) + k_) << 6],  \
                                       4, 0, 0);                               \
    } } while (0)

#define EREAD(DST, ADDR, IMM)                                                  \
  asm volatile("ds_read_b32 %0, %1 offset:" #IMM : "=v"(DST) : "v"(ADDR))

#define STEP(u, EC) do {                                                       \
    const int t_ = t0 + (u);                                                   \
    const float e_ = EC[(u)];                                                  \
    float es_;                                                                 \
    if (((u) & 1) != 0) { /* exact pow-2 rescale every 2 steps */              \
      const unsigned srf_ = __builtin_amdgcn_readfirstlane(__float_as_uint(s));\
      const int se_ = (int)((srf_ >> 23) & 0xFFu) - 127;                       \
      es_ = e_ * __uint_as_float((unsigned)(127 - se_) << 23);                 \
      E2 += se_;                                                               \
    } else { es_ = e_; }                                                       \
    float rot[16];                                                             \
    rot[0] = s;                                                                \
    rot[1] = DPPROR(s, 1);   rot[2] = DPPROR(s, 2);   rot[3] = DPPROR(s, 3);   \
    rot[4] = DPPROR(s, 4);   rot[5] = DPPROR(s, 5);   rot[6] = DPPROR(s, 6);   \
    rot[7] = DPPROR(s, 7);   rot[8] = DPPROR(s, 8);   rot[9] = DPPROR(s, 9);   \
    rot[10] = DPPROR(s, 10); rot[11] = DPPROR(s, 11); rot[12] = DPPROR(s, 12); \
    rot[13] = DPPROR(s, 13); rot[14] = DPPROR(s, 14); rot[15] = DPPROR(s, 15); \
    float q0a_ = aw[0]  * rot[0];                                              \
    float q1a_ = aw[16] * rot[0];                                              \
    float q2a_ = aw[32] * rot[0];                                              \
    float q3a_ = aw[48] * rot[0];                                              \
    float q0b_ = aw[8]  * rot[8];                                              \
    float q1b_ = aw[24] * rot[8];                                              \
    float q2b_ = aw[40] * rot[8];                                              \
    float q3b_ = aw[56] * rot[8];                                              \
    _Pragma("unroll")                                                          \
    for (int j_ = 1; j_ < 8; ++j_) {                                           \
      q0a_ = fmaf(aw[j_],      rot[j_], q0a_);                                 \
      q1a_ = fmaf(aw[16 + j_], rot[j_], q1a_);                                 \
      q2a_ = fmaf(aw[32 + j_], rot[j_], q2a_);                                 \
      q3a_ = fmaf(aw[48 + j_], rot[j_], q3a_);                                 \
      q0b_ = fmaf(aw[8 + j_],  rot[8 + j_], q0b_);                             \
      q1b_ = fmaf(aw[24 + j_], rot[8 + j_], q1b_);                             \
      q2b_ = fmaf(aw[40 + j_], rot[8 + j_], q2b_);                             \
      q3b_ = fmaf(aw[56 + j_], rot[8 + j_], q3b_);                             \
    }                                                                          \
    const float q0_ = q0a_ + q0b_;                                             \
    const float q1_ = q1a_ + q1b_;                                             \
    float q2_ = q2a_ + q2b_;                                                   \
    float q3_ = q3a_ + q3b_;                                                   \
    /* stage1 (xor32): give q2 (partner's = my group), q3 (buddy's) */         \
    float t2_, t3_;                                                            \
    asm("v_mov_b32 %0, %1" : "=v"(t2_) : "v"(q2_));                            \
    asm("v_mov_b32 %0, %1" : "=v"(t3_) : "v"(q3_));                            \
    asm("v_permlane32_swap_b32 %0, %1" : "+v"(q2_), "+v"(t2_));                \
    asm("v_permlane32_swap_b32 %0, %1" : "+v"(q3_), "+v"(t3_));                \
    const float pm_ = inA32 ? q2_ : t2_;   /* partner's give A (probed) */     \
    const float pn_ = inA32 ? q3_ : t3_;   /* partner's give B (probed) */     \
    const float ua_ = q0_ + pm_;   /* my group over chunks {c, c^2} */         \
    float ub_ = q1_ + pn_;         /* buddy group over {c, c^2}     */         \
    /* stage2 (xor16): give ub (partner's = my group over {c^1, c^3}) */       \
    float tg_;                                                                 \
    asm("v_mov_b32 %0, %1" : "=v"(tg_) : "v"(ub_));                            \
    asm("v_permlane16_swap_b32 %0, %1" : "+v"(ub_), "+v"(tg_));                \
    const float pg_ = inA16 ? ub_ : tg_;   /* partner's give (probed) */       \
    const float fin_ = ua_ + pg_;                                              \
    const float w_ = es_ * ((t_ == 0) ? pip : fin_);                           \
    if (t_ == Tn - 1) { vs = w_; e2s = E2; }                                   \
    s = w_;                                                                    \
  } while (0)

// one 4-step group: issue next group's 4 e-reads, exact-wait current's, run 4
#define GROUP(T0, ECUR, ENXT) do {                                             \
    const int t0 = (T0);                                                       \
    { const unsigned ea_ =                                                     \
          ebase + ((unsigned)(((t0 + 4) & 127)) << 8) + ((unsigned)lane << 2); \
      EREAD(ENXT[0], ea_, 0);   EREAD(ENXT[1], ea_, 256);                      \
      EREAD(ENXT[2], ea_, 512); EREAD(ENXT[3], ea_, 768); }                    \
    asm volatile("s_waitcnt lgkmcnt(4)");                                      \
    __builtin_amdgcn_sched_barrier(0);                                         \
    STEP(0, ECUR); STEP(1, ECUR); STEP(2, ECUR); STEP(3, ECUR);                \
  } while (0)

__global__ void __attribute__((amdgpu_flat_work_group_size(64, 64)))
__attribute__((amdgpu_waves_per_eu(1, 1)))
hmm_fwd(const int* __restrict__ x, const int* __restrict__ T,
        const float* __restrict__ ws, float* __restrict__ out) {
  const int lane = threadIdx.x;
  const int b = blockIdx.x;
  const float* __restrict__ ET = ws + ET_OFF;
  const int* __restrict__ xb = x + (size_t)b * TMAX;
  const int Tn = T[b];

  __shared__ __align__(16) float ebuf[128 * 64];  // 32 KB, 2 chunk halves
  const unsigned ebase = (unsigned)(size_t)ebuf;  // flat->LDS trunc

  // probe swap routing (R11 lesson: never assume direction semantics)
  bool inA32, inA16;
  {
    float qa = __int_as_float(lane), qb;
    asm("v_mov_b32 %0, %1" : "=v"(qb) : "v"(qa));
    asm("v_permlane32_swap_b32 %0, %1" : "+v"(qa), "+v"(qb));
    inA32 = (__float_as_int(qa) == (lane ^ 32));
    float pa = __int_as_float(lane), pb;
    asm("v_mov_b32 %0, %1" : "=v"(pb) : "v"(pa));
    asm("v_permlane16_swap_b32 %0, %1" : "+v"(pa), "+v"(pb));
    inA16 = (__float_as_int(pa) == (lane ^ 16));
  }

  // group-permuted swizzled A tile, pinned resident in VGPRs
  float aw[NS];
  {
    const float4* ar = (const float4*)(ws + ASW_OFF + lane * NS);
#pragma unroll
    for (int q = 0; q < 16; ++q) {
      float4 f = ar[q];
      aw[4 * q + 0] = f.x; aw[4 * q + 1] = f.y;
      aw[4 * q + 2] = f.z; aw[4 * q + 3] = f.w;
    }
  }
  PIN_AW();

  const float pip = ws[PIP_OFF + lane];

  // stage chunk 0, drain, prime group-0 e-reads
  int xcur = xb[lane];
  STAGE_CHUNK(xcur, 0);
  int xnext = xb[64 + lane];
  asm volatile("s_waitcnt vmcnt(0)" ::: "memory");

  float eA[4], eB[4];
  {
    const unsigned ea_ = ebase + ((unsigned)lane << 2);
    EREAD(eA[0], ea_, 0);   EREAD(eA[1], ea_, 256);
    EREAD(eA[2], ea_, 512); EREAD(eA[3], ea_, 768);
  }

  float s = 1.0f;   // exponent 0 -> se=0 at t=0
  float vs = 0.f;
  int E2 = 0, e2s = 0;

  const int nch = (Tn + 63) >> 6;
  for (int c = 0; c < nch; ++c) {
    const int tb = c << 6;
    if (c + 1 < TMAX / 64) STAGE_CHUNK(xnext, (c + 1) & 1);
    xnext = ((c + 2) < TMAX / 64) ? xb[((c + 2) << 6) + lane] : 0;
#pragma unroll 1
    for (int gp = 0; gp < 7; ++gp) {    // groups 0..13
      GROUP(tb + (gp << 3), eA, eB);
      GROUP(tb + (gp << 3) + 4, eB, eA);
    }
    GROUP(tb + 56, eA, eB);             // group 14
    // drain staging of chunk c+1 before group 15 issues next-chunk reads
    asm volatile("s_waitcnt vmcnt(0)" ::: "memory");
    GROUP(tb + 60, eB, eA);             // group 15 (loads eA for next chunk)
  }

  const float sf = wsum64(vs);
  if (lane == 0) {
    const double lp = (double)logf(sf) + (double)e2s * 0.6931471805599453;
    out[b] = (float)lp;
  }
}

extern "C" void kernel_launch(void* const* d_in, const int* in_sizes, int n_in,
                              void* d_out, int out_size, void* d_ws, size_t ws_size,
                              hipStream_t stream) {
  const int*   x  = (const int*)d_in[0];
  const int*   T  = (const int*)d_in[1];
  const float* pi = (const float*)d_in[2];
  const float* A  = (const float*)d_in[3];
  const float* E  = (const float*)d_in[4];
  float* out = (float*)d_out;
  float* ws  = (float*)d_ws;

  prep_small<<<1, 64, 0, stream>>>(pi, A, ws);
  emis_lse<<<NS, 256, 0, stream>>>(E, ws);
  emis_fill<<<(NS * NOBS + 255) / 256, 256, 0, stream>>>(E, ws);
  hmm_fwd<<<NB, 64, 0, stream>>>(x, T, ws, out);
}

// Round 20
// 374.573 us; speedup vs baseline: 1.0714x; 1.0177x over previous
//
#include <hip/hip_runtime.h>
#include <math.h>

#define NS   64
#define NOBS 10000
#define NB   256
#define TMAX 2048

// workspace layout (floats)
#define PIP_OFF 0
#define ASW_OFF 64                    // group-permuted, k-pair-interleaved A
#define LSE_OFF (64 + 4096)
#define ET_OFF  (64 + 4096 + 64)

__device__ __forceinline__ float wsum64(float v) {
  v += __shfl_xor(v, 1);
  v += __shfl_xor(v, 2);
  v += __shfl_xor(v, 4);
  v += __shfl_xor(v, 8);
  v += __shfl_xor(v, 16);
  v += __shfl_xor(v, 32);
  return v;
}

// DPP row_ror:N within 16-lane rows. Direction probed at prep time.
#define DPPROR(S, N)                                                           \
  __int_as_float(__builtin_amdgcn_update_dpp(                                  \
      0, __float_as_int(S), 0x120 + (N), 0xF, 0xF, true))

// ---------------- precompute: softmax(pi), column-softmax(A), swizzle ------
__global__ __launch_bounds__(64) void prep_small(const float* __restrict__ pi,
                                                 const float* __restrict__ A,
                                                 float* __restrict__ ws) {
  const int l = threadIdx.x;  // 0..63
  const int r = l & 15, c = l >> 4;
  float p = pi[l];
  float m = p;
  m = fmaxf(m, __shfl_xor(m, 1));
  m = fmaxf(m, __shfl_xor(m, 2));
  m = fmaxf(m, __shfl_xor(m, 4));
  m = fmaxf(m, __shfl_xor(m, 8));
  m = fmaxf(m, __shfl_xor(m, 16));
  m = fmaxf(m, __shfl_xor(m, 32));
  float ex = expf(p - m);
  float s = wsum64(ex);
  ws[PIP_OFF + l] = ex / s;

  __shared__ float Ap[NS * NS];
  float cm = -3.0e38f;
  for (int i = 0; i < NS; ++i) cm = fmaxf(cm, A[i * NS + l]);
  float cs = 0.f;
  for (int i = 0; i < NS; ++i) cs += expf(A[i * NS + l] - cm);
  float inv = 1.0f / cs;
  for (int i = 0; i < NS; ++i) Ap[i * NS + l] = expf(A[i * NS + l] - cm) * inv;
  __syncthreads();

  // probe the hardware's row_ror direction: does lane l receive (l-1)&15 ?
  const int probe = __builtin_amdgcn_update_dpp(0, l, 0x121, 0xF, 0xF, true);
  const int dir = ((probe & 15) == ((r - 1) & 15)) ? 1 : -1;  // uniform

  // group-permuted (slot m holds row-group c^m: q0/q1 = keep pair, q2/q3 =
  // give pair, R19-proven) + k-pair interleave for packed math:
  // float idx l*64 + m*16 + 2j   = A_{c^m}(k=j)    (pk lo lane)
  //           l*64 + m*16 + 2j+1 = A_{c^m}(k=j+8)  (pk hi lane)
  for (int m2 = 0; m2 < 4; ++m2)
    for (int j = 0; j < 8; ++j) {
      const int row = (r + 16 * (c ^ m2)) * NS;
      ws[ASW_OFF + l * 64 + m2 * 16 + 2 * j] =
          Ap[row + (16 * c + ((r - dir * j) & 15))];
      ws[ASW_OFF + l * 64 + m2 * 16 + 2 * j + 1] =
          Ap[row + (16 * c + ((r - dir * (j + 8)) & 15))];
    }
}

// ---------------- precompute: per-state emission logsumexp ----------------
__global__ __launch_bounds__(256) void emis_lse(const float* __restrict__ E,
                                                float* __restrict__ ws) {
  const int s = blockIdx.x;  // state
  const float* row = E + (size_t)s * NOBS;
  __shared__ float red[4];
  float m = -3.0e38f;
  for (int o = threadIdx.x; o < NOBS; o += 256) m = fmaxf(m, row[o]);
  m = fmaxf(m, __shfl_xor(m, 1));
  m = fmaxf(m, __shfl_xor(m, 2));
  m = fmaxf(m, __shfl_xor(m, 4));
  m = fmaxf(m, __shfl_xor(m, 8));
  m = fmaxf(m, __shfl_xor(m, 16));
  m = fmaxf(m, __shfl_xor(m, 32));
  const int wid = threadIdx.x >> 6;
  if ((threadIdx.x & 63) == 0) red[wid] = m;
  __syncthreads();
  m = fmaxf(fmaxf(red[0], red[1]), fmaxf(red[2], red[3]));
  __syncthreads();
  float sum = 0.f;
  for (int o = threadIdx.x; o < NOBS; o += 256) sum += expf(row[o] - m);
  sum = wsum64(sum);
  if ((threadIdx.x & 63) == 0) red[wid] = sum;
  __syncthreads();
  if (threadIdx.x == 0)
    ws[LSE_OFF + s] = m + logf(red[0] + red[1] + red[2] + red[3]);
}

// ---------------- precompute: EprobT[obs*64 + s] = exp(E[s,obs] - lse[s]) ----
__global__ __launch_bounds__(256) void emis_fill(const float* __restrict__ E,
                                                 float* __restrict__ ws) {
  const int idx = blockIdx.x * 256 + threadIdx.x;  // = obs*64 + s
  if (idx >= NS * NOBS) return;
  const int s = idx & 63;
  const int obs = idx >> 6;
  ws[ET_OFF + idx] = expf(E[(size_t)s * NOBS + obs] - ws[LSE_OFF + s]);
}

// ---------------- forward recursion: 1 batch = 1 block = 1 wave ----------------
// R19 (proven absmax 0.0, 340us) + packed matvec: 64 scalar fma -> 32
// v_pk_fma_f32 in ONE asm blob (4 group-chains interleaved, accumulators
// blob-internal -> no copies). k-halves packed per register pair: lo chain
// == R19's qXa_ (k=0..7, same order), hi == qXb_, q = lo+hi == qa+qb ->
// bitwise identical. rot pairs {rot[j], rot[j+8]} from the same 15 DPP movs.
// Butterfly/rescale/staging byte-identical to R19.

#define PINP(i)                                                                \
  asm volatile("" : "+v"(aw2[(i)].x), "+v"(aw2[(i)].y),                        \
                    "+v"(aw2[(i) + 1].x), "+v"(aw2[(i) + 1].y),                \
                    "+v"(aw2[(i) + 2].x), "+v"(aw2[(i) + 2].y),                \
                    "+v"(aw2[(i) + 3].x), "+v"(aw2[(i) + 3].y))
#define PIN_AW() do { PINP(0); PINP(4); PINP(8); PINP(12);                     \
                      PINP(16); PINP(20); PINP(24); PINP(28); } while (0)

// stage 64 emission rows of a chunk (x values in XS) into half HALF of ebuf
#define STAGE_CHUNK(XS, HALF) do {                                             \
    _Pragma("unroll")                                                          \
    for (int k_ = 0; k_ < 64; ++k_) {                                          \
      const int xt_ = __builtin_amdgcn_readlane((XS), k_);                     \
      const float* gp_ = ET + ((size_t)(unsigned)xt_ << 6) + lane;             \
      __builtin_amdgcn_global_load_lds(gp_, &ebuf[(((HALF) << 6) + k_) << 6],  \
                                       4, 0, 0);                               \
    } } while (0)

#define EREAD(DST, ADDR, IMM)                                                  \
  asm volatile("ds_read_b32 %0, %1 offset:" #IMM : "=v"(DST) : "v"(ADDR))

// all 4 group-chains, 4-way interleaved, packed: %0..%3 accs (float2),
// %4..%35 aw2[0..31], %36..%43 rp[0..7]
#define MV_PK(A0, A1, A2, A3)                                                  \
  asm("v_pk_mul_f32 %0, %4, %36\n\t"                                           \
      "v_pk_mul_f32 %1, %12, %36\n\t"                                          \
      "v_pk_mul_f32 %2, %20, %36\n\t"                                          \
      "v_pk_mul_f32 %3, %28, %36\n\t"                                          \
      "v_pk_fma_f32 %0, %5, %37, %0\n\t"                                       \
      "v_pk_fma_f32 %1, %13, %37, %1\n\t"                                      \
      "v_pk_fma_f32 %2, %21, %37, %2\n\t"                                      \
      "v_pk_fma_f32 %3, %29, %37, %3\n\t"                                      \
      "v_pk_fma_f32 %0, %6, %38, %0\n\t"                                       \
      "v_pk_fma_f32 %1, %14, %38, %1\n\t"                                      \
      "v_pk_fma_f32 %2, %22, %38, %2\n\t"                                      \
      "v_pk_fma_f32 %3, %30, %38, %3\n\t"                                      \
      "v_pk_fma_f32 %0, %7, %39, %0\n\t"                                       \
      "v_pk_fma_f32 %1, %15, %39, %1\n\t"                                      \
      "v_pk_fma_f32 %2, %23, %39, %2\n\t"                                      \
      "v_pk_fma_f32 %3, %31, %39, %3\n\t"                                      \
      "v_pk_fma_f32 %0, %8, %40, %0\n\t"                                       \
      "v_pk_fma_f32 %1, %16, %40, %1\n\t"                                      \
      "v_pk_fma_f32 %2, %24, %40, %2\n\t"                                      \
      "v_pk_fma_f32 %3, %32, %40, %3\n\t"                                      \
      "v_pk_fma_f32 %0, %9, %41, %0\n\t"                                       \
      "v_pk_fma_f32 %1, %17, %41, %1\n\t"                                      \
      "v_pk_fma_f32 %2, %25, %41, %2\n\t"                                      \
      "v_pk_fma_f32 %3, %33, %41, %3\n\t"                                      \
      "v_pk_fma_f32 %0, %10, %42, %0\n\t"                                      \
      "v_pk_fma_f32 %1, %18, %42, %1\n\t"                                      \
      "v_pk_fma_f32 %2, %26, %42, %2\n\t"                                      \
      "v_pk_fma_f32 %3, %34, %42, %3\n\t"                                      \
      "v_pk_fma_f32 %0, %11, %43, %0\n\t"                                      \
      "v_pk_fma_f32 %1, %19, %43, %1\n\t"                                      \
      "v_pk_fma_f32 %2, %27, %43, %2\n\t"                                      \
      "v_pk_fma_f32 %3, %35, %43, %3"                                          \
      : "=&v"(A0), "=&v"(A1), "=&v"(A2), "=&v"(A3)                             \
      : "v"(aw2[0]), "v"(aw2[1]), "v"(aw2[2]), "v"(aw2[3]),                    \
        "v"(aw2[4]), "v"(aw2[5]), "v"(aw2[6]), "v"(aw2[7]),                    \
        "v"(aw2[8]), "v"(aw2[9]), "v"(aw2[10]), "v"(aw2[11]),                  \
        "v"(aw2[12]), "v"(aw2[13]), "v"(aw2[14]), "v"(aw2[15]),                \
        "v"(aw2[16]), "v"(aw2[17]), "v"(aw2[18]), "v"(aw2[19]),                \
        "v"(aw2[20]), "v"(aw2[21]), "v"(aw2[22]), "v"(aw2[23]),                \
        "v"(aw2[24]), "v"(aw2[25]), "v"(aw2[26]), "v"(aw2[27]),                \
        "v"(aw2[28]), "v"(aw2[29]), "v"(aw2[30]), "v"(aw2[31]),                \
        "v"(rp[0]), "v"(rp[1]), "v"(rp[2]), "v"(rp[3]),                        \
        "v"(rp[4]), "v"(rp[5]), "v"(rp[6]), "v"(rp[7]))

#define STEP(u, EC) do {                                                       \
    const int t_ = t0 + (u);                                                   \
    const float e_ = EC[(u)];                                                  \
    float es_;                                                                 \
    if (((u) & 1) != 0) { /* exact pow-2 rescale every 2 steps */              \
      const unsigned srf_ = __builtin_amdgcn_readfirstlane(__float_as_uint(s));\
      const int se_ = (int)((srf_ >> 23) & 0xFFu) - 127;                       \
      es_ = e_ * __uint_as_float((unsigned)(127 - se_) << 23);                 \
      E2 += se_;                                                               \
    } else { es_ = e_; }                                                       \
    float2 rp[8];                                                              \
    rp[0].x = s;            rp[0].y = DPPROR(s, 8);                            \
    rp[1].x = DPPROR(s, 1); rp[1].y = DPPROR(s, 9);                            \
    rp[2].x = DPPROR(s, 2); rp[2].y = DPPROR(s, 10);                           \
    rp[3].x = DPPROR(s, 3); rp[3].y = DPPROR(s, 11);                           \
    rp[4].x = DPPROR(s, 4); rp[4].y = DPPROR(s, 12);                           \
    rp[5].x = DPPROR(s, 5); rp[5].y = DPPROR(s, 13);                           \
    rp[6].x = DPPROR(s, 6); rp[6].y = DPPROR(s, 14);                           \
    rp[7].x = DPPROR(s, 7); rp[7].y = DPPROR(s, 15);                           \
    float2 a0_, a1_, a2_, a3_;                                                 \
    MV_PK(a0_, a1_, a2_, a3_);                                                 \
    const float q0_ = a0_.x + a0_.y;                                           \
    const float q1_ = a1_.x + a1_.y;                                           \
    float q2_ = a2_.x + a2_.y;                                                 \
    float q3_ = a3_.x + a3_.y;                                                 \
    /* stage1 (xor32): give q2 (partner's = my group), q3 (buddy's) */         \
    float t2_, t3_;                                                            \
    asm("v_mov_b32 %0, %1" : "=v"(t2_) : "v"(q2_));                            \
    asm("v_mov_b32 %0, %1" : "=v"(t3_) : "v"(q3_));                            \
    asm("v_permlane32_swap_b32 %0, %1" : "+v"(q2_), "+v"(t2_));                \
    asm("v_permlane32_swap_b32 %0, %1" : "+v"(q3_), "+v"(t3_));                \
    const float pm_ = inA32 ? q2_ : t2_;   /* partner's give A (probed) */     \
    const float pn_ = inA32 ? q3_ : t3_;   /* partner's give B (probed) */     \
    const float ua_ = q0_ + pm_;   /* my group over chunks {c, c^2} */         \
    float ub_ = q1_ + pn_;         /* buddy group over {c, c^2}     */         \
    /* stage2 (xor16): give ub (partner's = my group over {c^1, c^3}) */       \
    float tg_;                                                                 \
    asm("v_mov_b32 %0, %1" : "=v"(tg_) : "v"(ub_));                            \
    asm("v_permlane16_swap_b32 %0, %1" : "+v"(ub_), "+v"(tg_));                \
    const float pg_ = inA16 ? ub_ : tg_;   /* partner's give (probed) */       \
    const float fin_ = ua_ + pg_;                                              \
    const float w_ = es_ * ((t_ == 0) ? pip : fin_);                           \
    if (t_ == Tn - 1) { vs = w_; e2s = E2; }                                   \
    s = w_;                                                                    \
  } while (0)

// one 4-step group: issue next group's 4 e-reads, exact-wait current's, run 4
#define GROUP(T0, ECUR, ENXT) do {                                             \
    const int t0 = (T0);                                                       \
    { const unsigned ea_ =                                                     \
          ebase + ((unsigned)(((t0 + 4) & 127)) << 8) + ((unsigned)lane << 2); \
      EREAD(ENXT[0], ea_, 0);   EREAD(ENXT[1], ea_, 256);                      \
      EREAD(ENXT[2], ea_, 512); EREAD(ENXT[3], ea_, 768); }                    \
    asm volatile("s_waitcnt lgkmcnt(4)");                                      \
    __builtin_amdgcn_sched_barrier(0);                                         \
    STEP(0, ECUR); STEP(1, ECUR); STEP(2, ECUR); STEP(3, ECUR);                \
  } while (0)

__global__ void __attribute__((amdgpu_flat_work_group_size(64, 64)))
__attribute__((amdgpu_waves_per_eu(1, 1)))
hmm_fwd(const int* __restrict__ x, const int* __restrict__ T,
        const float* __restrict__ ws, float* __restrict__ out) {
  const int lane = threadIdx.x;
  const int b = blockIdx.x;
  const float* __restrict__ ET = ws + ET_OFF;
  const int* __restrict__ xb = x + (size_t)b * TMAX;
  const int Tn = T[b];

  __shared__ __align__(16) float ebuf[128 * 64];  // 32 KB, 2 chunk halves
  const unsigned ebase = (unsigned)(size_t)ebuf;  // flat->LDS trunc

  // probe swap routing (R11 lesson: never assume direction semantics)
  bool inA32, inA16;
  {
    float qa = __int_as_float(lane), qb;
    asm("v_mov_b32 %0, %1" : "=v"(qb) : "v"(qa));
    asm("v_permlane32_swap_b32 %0, %1" : "+v"(qa), "+v"(qb));
    inA32 = (__float_as_int(qa) == (lane ^ 32));
    float pa = __int_as_float(lane), pb;
    asm("v_mov_b32 %0, %1" : "=v"(pb) : "v"(pa));
    asm("v_permlane16_swap_b32 %0, %1" : "+v"(pa), "+v"(pb));
    inA16 = (__float_as_int(pa) == (lane ^ 16));
  }

  // group-permuted, k-pair-interleaved A tile: aw2[g*8+j] = {A(k=j), A(k=j+8)}
  float2 aw2[32];
  {
    const float4* ar = (const float4*)(ws + ASW_OFF + lane * 64);
#pragma unroll
    for (int q = 0; q < 16; ++q) {
      float4 f = ar[q];
      aw2[2 * q]     = make_float2(f.x, f.y);
      aw2[2 * q + 1] = make_float2(f.z, f.w);
    }
  }
  PIN_AW();

  const float pip = ws[PIP_OFF + lane];

  // stage chunk 0, drain, prime group-0 e-reads
  int xcur = xb[lane];
  STAGE_CHUNK(xcur, 0);
  int xnext = xb[64 + lane];
  asm volatile("s_waitcnt vmcnt(0)" ::: "memory");

  float eA[4], eB[4];
  {
    const unsigned ea_ = ebase + ((unsigned)lane << 2);
    EREAD(eA[0], ea_, 0);   EREAD(eA[1], ea_, 256);
    EREAD(eA[2], ea_, 512); EREAD(eA[3], ea_, 768);
  }

  float s = 1.0f;   // exponent 0 -> se=0 at t=0
  float vs = 0.f;
  int E2 = 0, e2s = 0;

  const int nch = (Tn + 63) >> 6;
  for (int c = 0; c < nch; ++c) {
    const int tb = c << 6;
    if (c + 1 < TMAX / 64) STAGE_CHUNK(xnext, (c + 1) & 1);
    xnext = ((c + 2) < TMAX / 64) ? xb[((c + 2) << 6) + lane] : 0;
#pragma unroll 1
    for (int gp = 0; gp < 7; ++gp) {    // groups 0..13
      GROUP(tb + (gp << 3), eA, eB);
      GROUP(tb + (gp << 3) + 4, eB, eA);
    }
    GROUP(tb + 56, eA, eB);             // group 14
    // drain staging of chunk c+1 before group 15 issues next-chunk reads
    asm volatile("s_waitcnt vmcnt(0)" ::: "memory");
    GROUP(tb + 60, eB, eA);             // group 15 (loads eA for next chunk)
  }

  const float sf = wsum64(vs);
  if (lane == 0) {
    const double lp = (double)logf(sf) + (double)e2s * 0.6931471805599453;
    out[b] = (float)lp;
  }
}

extern "C" void kernel_launch(void* const* d_in, const int* in_sizes, int n_in,
                              void* d_out, int out_size, void* d_ws, size_t ws_size,
                              hipStream_t stream) {
  const int*   x  = (const int*)d_in[0];
  const int*   T  = (const int*)d_in[1];
  const float* pi = (const float*)d_in[2];
  const float* A  = (const float*)d_in[3];
  const float* E  = (const float*)d_in[4];
  float* out = (float*)d_out;
  float* ws  = (float*)d_ws;

  prep_small<<<1, 64, 0, stream>>>(pi, A, ws);
  emis_lse<<<NS, 256, 0, stream>>>(E, ws);
  emis_fill<<<(NS * NOBS + 255) / 256, 256, 0, stream>>>(E, ws);
  hmm_fwd<<<NB, 64, 0, stream>>>(x, T, ws, out);
}